// Round 1
// baseline (330.632 us; speedup 1.0000x reference)
//
#include <hip/hip_runtime.h>
#include <math.h>

constexpr int NROW = 8192;
constexpr int FD   = 256;

// ws layout (bytes):
//   0      : float scal[8]   {a0,a1,b0,b1,A,B,-,-}
//   1024   : float nrm[8192] (32 KB)
//   65536  : float c[256]    (1 KB)
//   66560  : float G[65536]  (256 KB)
//   524288 : float emb[8192*256] (8 MB)

__global__ void k_scal(const float* __restrict__ linear,
                       const float* __restrict__ dirv,
                       const float* __restrict__ feat,
                       float* __restrict__ scal) {
    int lane = threadIdx.x;  // 64 threads = 1 wave
    for (int i = 0; i < 2; ++i) {
        float pa = 0.f, pb = 0.f;
        for (int k = lane; k < FD; k += 64) {
            float l = linear[i*FD + k];
            pa += feat[i*FD + k] * l;
            pb += dirv[i*FD + k] * l;
        }
        #pragma unroll
        for (int off = 32; off; off >>= 1) {
            pa += __shfl_down(pa, off);
            pb += __shfl_down(pb, off);
        }
        if (lane == 0) { scal[i] = pa; scal[2 + i] = pb; }
    }
}

// one wave per row: n_j = ||row_j||^2
__global__ void k_norm(const float* __restrict__ in, float* __restrict__ nrm) {
    int wave = threadIdx.x >> 6, lane = threadIdx.x & 63;
    int row = blockIdx.x * 4 + wave;
    const float4 v = ((const float4*)(in + row * FD))[lane];
    float s = v.x*v.x + v.y*v.y + v.z*v.z + v.w*v.w;
    #pragma unroll
    for (int off = 32; off; off >>= 1) s += __shfl_down(s, off);
    if (lane == 0) nrm[row] = s;
}

// single block: F2 = sum(nrm); derive A=a, B=sign(b)/sqrt(F2)
__global__ void k_red(const float* __restrict__ nrm, float* __restrict__ scal, int depth) {
    __shared__ float l[256];
    float s = 0.f;
    for (int j = threadIdx.x; j < NROW; j += 256) s += nrm[j];
    l[threadIdx.x] = s;
    __syncthreads();
    for (int off = 128; off; off >>= 1) {
        if ((int)threadIdx.x < off) l[threadIdx.x] += l[threadIdx.x + off];
        __syncthreads();
    }
    if (threadIdx.x == 0) {
        float F2 = l[0];
        float a = scal[depth], b = scal[2 + depth];
        float sb = (b > 0.f) ? 1.f : ((b < 0.f) ? -1.f : 0.f);
        scal[4] = a;
        scal[5] = sb / sqrtf(F2);
    }
}

// per-row scale: emb'[j] = f_j * in[j];  also accumulate c = colsum(emb')
__global__ void k_scale(const float* __restrict__ in, float* __restrict__ emb,
                        const float* __restrict__ nrm, const float* __restrict__ scal,
                        float* __restrict__ c) {
    int k = threadIdx.x;           // column
    int r0 = blockIdx.x * 32;
    float A = scal[4], B = scal[5];
    float csum = 0.f;
    for (int j = r0; j < r0 + 32; ++j) {
        float nj = nrm[j];
        float inner = A * B * nj;
        float scl = (inner <= 0.f) ? inner : 0.f;   // where(inner<=0, inner, 0)
        float f = A - scl * B;
        float v = f * in[j*FD + k];
        emb[j*FD + k] = v;
        csum += v;
    }
    atomicAdd(&c[k], csum);
}

// G = emb^T emb : grid (4,4,32), 64x64 tile per (x,y), 256-row K-chunk per z
__global__ void k_gram(const float* __restrict__ emb, float* __restrict__ G) {
    __shared__ float As[32][64];
    __shared__ float Bs[32][64];
    int ti = blockIdx.x, tj = blockIdx.y;
    int m0 = blockIdx.z * 256;
    int tid = threadIdx.x;
    int tx = tid & 15, ty = tid >> 4;
    float acc[4][4] = {};
    for (int mc = 0; mc < 256; mc += 32) {
        __syncthreads();
        for (int idx = tid; idx < 32*64; idx += 256) {
            int mm = idx >> 6, p = idx & 63;
            As[mm][p] = emb[(m0 + mc + mm)*FD + ti*64 + p];
            Bs[mm][p] = emb[(m0 + mc + mm)*FD + tj*64 + p];
        }
        __syncthreads();
        #pragma unroll 8
        for (int mm = 0; mm < 32; ++mm) {
            float4 a4 = *(const float4*)&As[mm][ty*4];
            float4 b4 = *(const float4*)&Bs[mm][tx*4];
            float av[4] = {a4.x, a4.y, a4.z, a4.w};
            float bv[4] = {b4.x, b4.y, b4.z, b4.w};
            #pragma unroll
            for (int r = 0; r < 4; ++r)
                #pragma unroll
                for (int cc = 0; cc < 4; ++cc)
                    acc[r][cc] += av[r] * bv[cc];
        }
    }
    #pragma unroll
    for (int r = 0; r < 4; ++r)
        #pragma unroll
        for (int cc = 0; cc < 4; ++cc)
            atomicAdd(&G[(ti*64 + ty*4 + r)*FD + (tj*64 + tx*4 + cc)], acc[r][cc]);
}

// emb[j] += (emb[j]@G - (emb[j].c) * emb[j]) / N ; 16 rows per block
__global__ void k_apply(float* __restrict__ emb, const float* __restrict__ G,
                        const float* __restrict__ c) {
    __shared__ float rows[16][FD];
    __shared__ float u[16];
    int tid = threadIdx.x;
    int r0 = blockIdx.x * 16;
    for (int idx = tid; idx < 16*FD; idx += 256)
        rows[idx >> 8][idx & 255] = emb[(r0 + (idx >> 8))*FD + (idx & 255)];
    __syncthreads();
    int wave = tid >> 6, lane = tid & 63;
    for (int j = wave; j < 16; j += 4) {
        const float4 rv = ((const float4*)rows[j])[lane];
        const float4 cv = ((const float4*)c)[lane];
        float s = rv.x*cv.x + rv.y*cv.y + rv.z*cv.z + rv.w*cv.w;
        #pragma unroll
        for (int off = 32; off; off >>= 1) s += __shfl_down(s, off);
        if (lane == 0) u[j] = s;
    }
    __syncthreads();
    float acc[16];
    #pragma unroll
    for (int j = 0; j < 16; ++j) acc[j] = 0.f;
    for (int m = 0; m < FD; m += 4) {
        float g0 = G[(m+0)*FD + tid];
        float g1 = G[(m+1)*FD + tid];
        float g2 = G[(m+2)*FD + tid];
        float g3 = G[(m+3)*FD + tid];
        #pragma unroll
        for (int j = 0; j < 16; ++j) {
            float4 rv = *(const float4*)&rows[j][m];
            acc[j] += rv.x*g0 + rv.y*g1 + rv.z*g2 + rv.w*g3;
        }
    }
    const float invN = 1.0f / NROW;
    #pragma unroll
    for (int j = 0; j < 16; ++j) {
        float v = rows[j][tid];
        emb[(r0 + j)*FD + tid] = v + (acc[j] - u[j]*v) * invN;
    }
}

__global__ void k_colsum(const float* __restrict__ emb, float* __restrict__ c) {
    int k = threadIdx.x;
    int r0 = blockIdx.x * 32;
    float s = 0.f;
    for (int j = r0; j < r0 + 32; ++j) s += emb[j*FD + k];
    atomicAdd(&c[k], s);
}

// out[j] = dot(emb_j, c) / N  for j < N-1
__global__ void k_out(const float* __restrict__ emb, const float* __restrict__ c,
                      float* __restrict__ out) {
    int wave = threadIdx.x >> 6, lane = threadIdx.x & 63;
    int row = blockIdx.x * 4 + wave;
    const float4 v = ((const float4*)(emb + row*FD))[lane];
    const float4 cv = ((const float4*)c)[lane];
    float s = v.x*cv.x + v.y*cv.y + v.z*cv.z + v.w*cv.w;
    #pragma unroll
    for (int off = 32; off; off >>= 1) s += __shfl_down(s, off);
    if (lane == 0 && row < NROW - 1) out[row] = s * (1.0f / NROW);
}

extern "C" void kernel_launch(void* const* d_in, const int* in_sizes, int n_in,
                              void* d_out, int out_size, void* d_ws, size_t ws_size,
                              hipStream_t stream) {
    const float* X      = (const float*)d_in[0];
    // d_in[1] = coefs (unused by the reference forward)
    const float* linear = (const float*)d_in[2];
    const float* dirv   = (const float*)d_in[3];
    const float* feat   = (const float*)d_in[4];
    float* out = (float*)d_out;

    char* ws = (char*)d_ws;
    float* scal = (float*)(ws + 0);
    float* nrm  = (float*)(ws + 1024);
    float* c    = (float*)(ws + 65536);
    float* G    = (float*)(ws + 66560);
    float* emb  = (float*)(ws + 524288);

    k_scal<<<1, 64, 0, stream>>>(linear, dirv, feat, scal);

    for (int d = 0; d < 2; ++d) {
        const float* in = (d == 0) ? X : emb;
        k_norm<<<NROW/4, 256, 0, stream>>>(in, nrm);
        k_red<<<1, 256, 0, stream>>>(nrm, scal, d);
        hipMemsetAsync(ws + 65536, 0, 1024 + 65536*4, stream);  // zero c + G
        k_scale<<<NROW/32, 256, 0, stream>>>(in, emb, nrm, scal, c);
        k_gram<<<dim3(4,4,32), 256, 0, stream>>>(emb, G);
        k_apply<<<NROW/16, 256, 0, stream>>>(emb, G, c);
    }

    hipMemsetAsync(ws + 65536, 0, 1024, stream);  // zero c
    k_colsum<<<NROW/32, 256, 0, stream>>>(emb, c);
    k_out<<<NROW/4, 256, 0, stream>>>(emb, c, out);
}

// Round 2
// 276.488 us; speedup vs baseline: 1.1958x; 1.1958x over previous
//
#include <hip/hip_runtime.h>
#include <math.h>

constexpr int NROW = 8192;
constexpr int FD   = 256;

// ws layout (bytes):
//   0       : float scal[8]  {a0,a1,b0,b1,A,B,A*B,-}
//   4096    : float nrm[8192]          (32 KB)
//   36864   : float fpart[2048]        (8 KB)   per-block ||row||^2 partials
//   45056   : float cpart[32*256]      (32 KB)  per-z colsum partials (scaled rows)
//   98304   : float G[256*256]         (256 KB)
//   524288  : float cpart2[512*256]    (512 KB) final colsum partials
//   1048576 : float emb[8192*256]      (8 MB)   updated in place across depths
//   9437184 : float Gp[NZ*256*256]     (NZ * 256 KB) gram partials (fallback: aliases cpart2)

__global__ void k_scal(const float* __restrict__ linear,
                       const float* __restrict__ dirv,
                       const float* __restrict__ feat,
                       float* __restrict__ scal) {
    int lane = threadIdx.x;  // 64 threads = 1 wave
    for (int i = 0; i < 2; ++i) {
        float pa = 0.f, pb = 0.f;
        for (int k = lane; k < FD; k += 64) {
            float l = linear[i*FD + k];
            pa += feat[i*FD + k] * l;
            pb += dirv[i*FD + k] * l;
        }
        #pragma unroll
        for (int off = 32; off; off >>= 1) {
            pa += __shfl_down(pa, off);
            pb += __shfl_down(pb, off);
        }
        if (lane == 0) { scal[i] = pa; scal[2 + i] = pb; }
    }
}

// one wave per row: nrm[j] = ||row_j||^2 ; block partial sum -> fpart
__global__ void k_norm(const float* __restrict__ in, float* __restrict__ nrm,
                       float* __restrict__ fpart) {
    __shared__ float bs[4];
    int wave = threadIdx.x >> 6, lane = threadIdx.x & 63;
    int row = blockIdx.x * 4 + wave;
    const float4 v = ((const float4*)(in + (size_t)row * FD))[lane];
    float s = v.x*v.x + v.y*v.y + v.z*v.z + v.w*v.w;
    #pragma unroll
    for (int off = 32; off; off >>= 1) s += __shfl_down(s, off);
    if (lane == 0) { nrm[row] = s; bs[wave] = s; }
    __syncthreads();
    if (threadIdx.x == 0) fpart[blockIdx.x] = bs[0] + bs[1] + bs[2] + bs[3];
}

// single block: F2 = sum(fpart); scalars A=a, B=sign(b)/||emb||, AB
__global__ void k_red(const float* __restrict__ fpart, float* __restrict__ scal, int depth) {
    __shared__ float l[256];
    float s = 0.f;
    for (int j = threadIdx.x; j < 2048; j += 256) s += fpart[j];
    l[threadIdx.x] = s;
    __syncthreads();
    for (int off = 128; off; off >>= 1) {
        if ((int)threadIdx.x < off) l[threadIdx.x] += l[threadIdx.x + off];
        __syncthreads();
    }
    if (threadIdx.x == 0) {
        float F2 = l[0];
        float a = scal[depth], b = scal[2 + depth];
        float sb = (b > 0.f) ? 1.f : ((b < 0.f) ? -1.f : 0.f);
        float B = sb / sqrtf(F2);
        scal[4] = a;
        scal[5] = B;
        scal[6] = a * B;
    }
}

// Gram partials: grid (4,4,NZ). Scales rows on the fly (A-side by f^2).
// tj==0 blocks also emit colsum partials of scaled rows -> cpart[z][col].
__global__ void k_gram(const float* __restrict__ in, const float* __restrict__ nrm,
                       const float* __restrict__ scal, float* __restrict__ Gp,
                       float* __restrict__ cpart) {
    __shared__ float As[32][64];
    __shared__ float Bs[32][64];
    __shared__ float frow[32];
    const int ti = blockIdx.x, tj = blockIdx.y, z = blockIdx.z;
    const int NZ = gridDim.z;
    const int KR = NROW / NZ;
    const int m0 = z * KR;
    const int tid = threadIdx.x;
    const int tx = tid & 15, ty = tid >> 4;
    const int p = tid & 63, q = tid >> 6;
    const float A = scal[4], B = scal[5], AB = scal[6];
    float acc[4][4] = {};
    float cs = 0.f;
    for (int mc = m0; mc < m0 + KR; mc += 32) {
        __syncthreads();
        if (tid < 32) {
            float inner = AB * nrm[mc + tid];
            frow[tid] = A - (inner <= 0.f ? inner : 0.f) * B;
        }
        #pragma unroll
        for (int r = 0; r < 2; ++r) {
            int idx = tid + r * 256;
            int mm = idx >> 4, c4 = (idx & 15) << 2;
            const float* rp = in + (size_t)(mc + mm) * FD;
            *(float4*)&As[mm][c4] = *(const float4*)&rp[ti*64 + c4];
            *(float4*)&Bs[mm][c4] = *(const float4*)&rp[tj*64 + c4];
        }
        __syncthreads();
        #pragma unroll 8
        for (int mm = 0; mm < 32; ++mm) {
            float f = frow[mm], f2 = f * f;
            float4 a4 = *(const float4*)&As[mm][ty*4];
            float4 b4 = *(const float4*)&Bs[mm][tx*4];
            float av[4] = {a4.x*f2, a4.y*f2, a4.z*f2, a4.w*f2};
            float bv[4] = {b4.x, b4.y, b4.z, b4.w};
            #pragma unroll
            for (int r = 0; r < 4; ++r)
                #pragma unroll
                for (int cc = 0; cc < 4; ++cc)
                    acc[r][cc] += av[r] * bv[cc];
        }
        if (tj == 0) {
            #pragma unroll
            for (int s = 0; s < 8; ++s) cs += frow[q*8 + s] * As[q*8 + s][p];
        }
    }
    float* gp = Gp + (size_t)z * (FD * FD);
    #pragma unroll
    for (int r = 0; r < 4; ++r) {
        float4 o = make_float4(acc[r][0], acc[r][1], acc[r][2], acc[r][3]);
        *(float4*)&gp[(ti*64 + ty*4 + r)*FD + tj*64 + tx*4] = o;
    }
    if (tj == 0) {
        __syncthreads();
        ((float*)As)[q*64 + p] = cs;
        __syncthreads();
        if (tid < 64)
            cpart[z*FD + ti*64 + tid] = ((float*)As)[tid] + ((float*)As)[64 + tid] +
                                        ((float*)As)[128 + tid] + ((float*)As)[192 + tid];
    }
}

// reduce Gp partials -> G
__global__ void k_gred(const float* __restrict__ Gp, float* __restrict__ G, int NZ) {
    int e0 = (blockIdx.x * 256 + threadIdx.x) * 4;
    float4 s = make_float4(0.f, 0.f, 0.f, 0.f);
    for (int z = 0; z < NZ; ++z) {
        float4 v = *(const float4*)&Gp[(size_t)z * (FD * FD) + e0];
        s.x += v.x; s.y += v.y; s.z += v.z; s.w += v.w;
    }
    *(float4*)&G[e0] = s;
}

// emb_out[j] = r_j + (r_j@G - (r_j.c) r_j)/N with r_j = f_j * in_j (scaled on the fly)
// 16 rows/block, grid 512. Wave w: all 16 rows x 64-col chunk; lane = rq*16+cx.
__global__ void k_apply(const float* __restrict__ in, const float* __restrict__ nrm,
                        const float* __restrict__ scal, const float* __restrict__ G,
                        const float* __restrict__ cpart, int NZ,
                        float* __restrict__ emb, float* __restrict__ cpart2, int emit) {
    __shared__ float rows[16][FD + 4];
    __shared__ float csh[FD];
    __shared__ float ff[16];
    __shared__ float u[16];
    const int tid = threadIdx.x;
    const int r0 = blockIdx.x * 16;
    const float A = scal[4], B = scal[5], AB = scal[6];

    float cv = 0.f;
    #pragma unroll 4
    for (int z = 0; z < NZ; ++z) cv += cpart[z*FD + tid];
    csh[tid] = cv;
    if (tid < 16) {
        float inner = AB * nrm[r0 + tid];
        ff[tid] = A - (inner <= 0.f ? inner : 0.f) * B;
    }
    __syncthreads();

    #pragma unroll
    for (int r = 0; r < 4; ++r) {
        int idx = tid + r * 256;
        int j = idx >> 6, c4 = (idx & 63) << 2;
        float4 v = *(const float4*)&in[(size_t)(r0 + j) * FD + c4];
        float f = ff[j];
        v.x *= f; v.y *= f; v.z *= f; v.w *= f;
        *(float4*)&rows[j][c4] = v;
    }
    __syncthreads();

    const int wave = tid >> 6, lane = tid & 63;
    for (int j = wave; j < 16; j += 4) {
        float4 rv = *(const float4*)&rows[j][lane*4];
        float4 cc = ((const float4*)csh)[lane];
        float s = rv.x*cc.x + rv.y*cc.y + rv.z*cc.z + rv.w*cc.w;
        #pragma unroll
        for (int off = 32; off; off >>= 1) s += __shfl_down(s, off);
        if (lane == 0) u[j] = s;
    }
    __syncthreads();

    const int rq = lane >> 4, cx = lane & 15;
    const int c0 = wave * 64 + cx * 4;     // this thread's 4 output cols
    const int jb = rq * 4;                 // this thread's 4 rows
    float acc[4][4] = {};                  // [jj][cc]
    for (int m = 0; m < FD; m += 4) {
        float4 g0 = *(const float4*)&G[(m+0)*FD + c0];
        float4 g1 = *(const float4*)&G[(m+1)*FD + c0];
        float4 g2 = *(const float4*)&G[(m+2)*FD + c0];
        float4 g3 = *(const float4*)&G[(m+3)*FD + c0];
        #pragma unroll
        for (int jj = 0; jj < 4; ++jj) {
            float4 rv = *(const float4*)&rows[jb + jj][m];
            acc[jj][0] += rv.x*g0.x + rv.y*g1.x + rv.z*g2.x + rv.w*g3.x;
            acc[jj][1] += rv.x*g0.y + rv.y*g1.y + rv.z*g2.y + rv.w*g3.y;
            acc[jj][2] += rv.x*g0.z + rv.y*g1.z + rv.z*g2.z + rv.w*g3.z;
            acc[jj][3] += rv.x*g0.w + rv.y*g1.w + rv.z*g2.w + rv.w*g3.w;
        }
    }

    const float invN = 1.0f / NROW;
    float4 osum = make_float4(0.f, 0.f, 0.f, 0.f);
    #pragma unroll
    for (int jj = 0; jj < 4; ++jj) {
        int j = jb + jj;
        float4 v = *(const float4*)&rows[j][c0];
        float uj = u[j];
        float4 o;
        o.x = v.x + (acc[jj][0] - uj*v.x) * invN;
        o.y = v.y + (acc[jj][1] - uj*v.y) * invN;
        o.z = v.z + (acc[jj][2] - uj*v.z) * invN;
        o.w = v.w + (acc[jj][3] - uj*v.w) * invN;
        *(float4*)&emb[(size_t)(r0 + j) * FD + c0] = o;
        osum.x += o.x; osum.y += o.y; osum.z += o.z; osum.w += o.w;
    }
    if (emit) {
        __syncthreads();                       // rows[] reads all done
        *(float4*)&rows[rq][wave*64 + cx*4] = osum;
        __syncthreads();
        if (tid < 256)
            cpart2[(size_t)blockIdx.x * FD + tid] =
                rows[0][tid] + rows[1][tid] + rows[2][tid] + rows[3][tid];
    }
}

// out[j] = dot(emb_j, c)/N, c = sum of 512 cpart2 partials
__global__ void k_out(const float* __restrict__ emb, const float* __restrict__ cpart2,
                      float* __restrict__ out) {
    __shared__ float c2[FD];
    int tid = threadIdx.x;
    float s = 0.f;
    #pragma unroll 8
    for (int pp = 0; pp < 512; ++pp) s += cpart2[(size_t)pp * FD + tid];
    c2[tid] = s;
    __syncthreads();
    int wave = tid >> 6, lane = tid & 63;
    int r0 = blockIdx.x * 64;
    for (int j = wave; j < 64; j += 4) {
        int row = r0 + j;
        float4 v = ((const float4*)(emb + (size_t)row * FD))[lane];
        float4 cc = ((const float4*)c2)[lane];
        float t = v.x*cc.x + v.y*cc.y + v.z*cc.z + v.w*cc.w;
        #pragma unroll
        for (int off = 32; off; off >>= 1) t += __shfl_down(t, off);
        if (lane == 0 && row < NROW - 1) out[row] = t * (1.0f / NROW);
    }
}

extern "C" void kernel_launch(void* const* d_in, const int* in_sizes, int n_in,
                              void* d_out, int out_size, void* d_ws, size_t ws_size,
                              hipStream_t stream) {
    const float* X      = (const float*)d_in[0];
    // d_in[1] = coefs (unused by the reference forward)
    const float* linear = (const float*)d_in[2];
    const float* dirv   = (const float*)d_in[3];
    const float* feat   = (const float*)d_in[4];
    float* out = (float*)d_out;

    char* ws = (char*)d_ws;
    float* scal   = (float*)(ws + 0);
    float* nrm    = (float*)(ws + 4096);
    float* fpart  = (float*)(ws + 36864);
    float* cpart  = (float*)(ws + 45056);
    float* G      = (float*)(ws + 98304);
    float* cpart2 = (float*)(ws + 524288);
    float* emb    = (float*)(ws + 1048576);

    // Gram partial buffer: prefer dedicated region after emb; else alias cpart2 (NZ=2).
    const size_t gp_off = 9437184;
    float* Gp;
    int NZ;
    if (ws_size >= gp_off + 262144) {
        NZ = 1;
        while (NZ < 32 && ws_size >= gp_off + (size_t)(NZ * 2) * 262144) NZ *= 2;
        Gp = (float*)(ws + gp_off);
    } else {
        NZ = 2;                       // 512 KB, aliases cpart2 (dead at that point)
        Gp = (float*)(ws + 524288);
    }

    k_scal<<<1, 64, 0, stream>>>(linear, dirv, feat, scal);

    for (int d = 0; d < 2; ++d) {
        const float* in = (d == 0) ? X : emb;
        k_norm<<<NROW/4, 256, 0, stream>>>(in, nrm, fpart);
        k_red<<<1, 256, 0, stream>>>(fpart, scal, d);
        k_gram<<<dim3(4,4,NZ), 256, 0, stream>>>(in, nrm, scal, Gp, cpart);
        k_gred<<<64, 256, 0, stream>>>(Gp, G, NZ);
        k_apply<<<NROW/16, 256, 0, stream>>>(in, nrm, scal, G, cpart, NZ,
                                             emb, cpart2, d == 1 ? 1 : 0);
    }

    k_out<<<128, 256, 0, stream>>>(emb, cpart2, out);
}

// Round 3
// 179.143 us; speedup vs baseline: 1.8456x; 1.5434x over previous
//
#include <hip/hip_runtime.h>
#include <math.h>

constexpr int NROW = 8192;
constexpr int FD   = 256;
constexpr int NZ   = 32;

// ws layout (bytes), total exactly 9437184 (fits the inferred ~9 MB ws):
//   0       : float scal[8]  {a0,a1,b0,b1,A,B,AB,F2}
//   4096    : float nrm0[8192]   (32 KB)
//   36864   : float nrm1[8192]   (32 KB)
//   69632   : float fpart[2048]  (8 KB)   (reused as fpart1[512] after red0)
//   77824   : float cpart[32*256](32 KB)
//   110592  : float c0[256]      (1 KB)
//   112640  : float G0[65536]    (256 KB)
//   375808  : float spart[128*256](128 KB)
//   506880  : float u[8192]      (32 KB)
//   539648  : float vpart[128*256](128 KB)
//   1048576 : float emb[8192*256] (8 MB)  — doubles as Gp0[32][65536] before apply0

__device__ __forceinline__ float f_of(float nj, float A, float B, float AB) {
    float inner = AB * nj;
    return A - (inner <= 0.f ? inner : 0.f) * B;
}

// one wave per row: nrm0[j] = ||row||^2 ; block partial -> fpart
__global__ void k_norm(const float* __restrict__ in, float* __restrict__ nrm,
                       float* __restrict__ fpart) {
    __shared__ float bs[4];
    int wave = threadIdx.x >> 6, lane = threadIdx.x & 63;
    int row = blockIdx.x * 4 + wave;
    const float4 v = *(const float4*)&in[(size_t)row * FD + lane * 4];
    float s = v.x*v.x + v.y*v.y + v.z*v.z + v.w*v.w;
    #pragma unroll
    for (int off = 32; off; off >>= 1) s += __shfl_down(s, off);
    if (lane == 0) { nrm[row] = s; bs[wave] = s; }
    __syncthreads();
    if (threadIdx.x == 0) fpart[blockIdx.x] = bs[0] + bs[1] + bs[2] + bs[3];
}

// 1 block: (optionally) a,b dots; F2 = sum(fpart[0..n)); scalars A,B,AB
__global__ void k_red(const float* __restrict__ fpart, int n, float* __restrict__ scal,
                      int depth, const float* __restrict__ linear,
                      const float* __restrict__ dirv, const float* __restrict__ feat,
                      int do_scal) {
    __shared__ float l[256];
    int tid = threadIdx.x;
    if (do_scal && tid < 64) {
        for (int i = 0; i < 2; ++i) {
            float pa = 0.f, pb = 0.f;
            for (int k = tid; k < FD; k += 64) {
                float ll = linear[i*FD + k];
                pa += feat[i*FD + k] * ll;
                pb += dirv[i*FD + k] * ll;
            }
            #pragma unroll
            for (int off = 32; off; off >>= 1) {
                pa += __shfl_down(pa, off);
                pb += __shfl_down(pb, off);
            }
            if (tid == 0) { scal[i] = pa; scal[2 + i] = pb; }
        }
    }
    float s = 0.f;
    for (int j = tid; j < n; j += 256) s += fpart[j];
    l[tid] = s;
    __syncthreads();
    for (int off = 128; off; off >>= 1) {
        if (tid < off) l[tid] += l[tid + off];
        __syncthreads();
    }
    if (tid == 0) {
        float F2 = l[0];
        float a = scal[depth], b = scal[2 + depth];
        float sb = (b > 0.f) ? 1.f : ((b < 0.f) ? -1.f : 0.f);
        float B = sb / sqrtf(F2);
        scal[4] = a; scal[5] = B; scal[6] = a * B; scal[7] = F2;
    }
}

// Gram partials of r0 = f0*X: grid (4,4,32); both sides scaled at stage time.
// tj==0 blocks emit cpart[z][col] = colsum of scaled rows (their K-range).
__global__ void __launch_bounds__(256, 2)
k_gram(const float* __restrict__ X, const float* __restrict__ nrm0,
       const float* __restrict__ scal, float* __restrict__ Gp,
       float* __restrict__ cpart) {
    __shared__ float As[32][64];
    __shared__ float Bs[32][64];
    const int ti = blockIdx.x, tj = blockIdx.y, z = blockIdx.z;
    const int m0 = z * (NROW / NZ);            // KR = 256
    const int tid = threadIdx.x;
    const int tx = tid & 15, ty = tid >> 4;
    const int p = tid & 63, q = tid >> 6;
    const float A = scal[4], B = scal[5], AB = scal[6];
    float acc[4][4] = {};
    float cs = 0.f;
    for (int mc = m0; mc < m0 + (NROW / NZ); mc += 32) {
        __syncthreads();
        #pragma unroll
        for (int r = 0; r < 2; ++r) {
            int idx = tid + r * 256;
            int mm = idx >> 4, c4 = (idx & 15) << 2;
            int row = mc + mm;
            float f = f_of(nrm0[row], A, B, AB);
            const float* rp = X + (size_t)row * FD;
            float4 a = *(const float4*)&rp[ti*64 + c4];
            float4 b = *(const float4*)&rp[tj*64 + c4];
            a.x *= f; a.y *= f; a.z *= f; a.w *= f;
            b.x *= f; b.y *= f; b.z *= f; b.w *= f;
            *(float4*)&As[mm][c4] = a;
            *(float4*)&Bs[mm][c4] = b;
        }
        __syncthreads();
        #pragma unroll 8
        for (int mm = 0; mm < 32; ++mm) {
            float4 a4 = *(const float4*)&As[mm][ty*4];
            float4 b4 = *(const float4*)&Bs[mm][tx*4];
            float av[4] = {a4.x, a4.y, a4.z, a4.w};
            float bv[4] = {b4.x, b4.y, b4.z, b4.w};
            #pragma unroll
            for (int r = 0; r < 4; ++r)
                #pragma unroll
                for (int cc = 0; cc < 4; ++cc)
                    acc[r][cc] += av[r] * bv[cc];
        }
        if (tj == 0) {
            #pragma unroll
            for (int s = 0; s < 8; ++s) cs += As[q*8 + s][p];
        }
    }
    float* gp = Gp + (size_t)z * (FD * FD);
    #pragma unroll
    for (int r = 0; r < 4; ++r) {
        float4 o = make_float4(acc[r][0], acc[r][1], acc[r][2], acc[r][3]);
        *(float4*)&gp[(ti*64 + ty*4 + r)*FD + tj*64 + tx*4] = o;
    }
    if (tj == 0) {
        __syncthreads();
        ((float*)As)[q*64 + p] = cs;
        __syncthreads();
        if (tid < 64)
            cpart[z*FD + ti*64 + tid] = ((float*)As)[tid] + ((float*)As)[64 + tid] +
                                        ((float*)As)[128 + tid] + ((float*)As)[192 + tid];
    }
}

// reduce Gp -> G0 (blocks 0..63) ; cpart -> c0 (block 64)
__global__ void k_gred(const float* __restrict__ Gp, const float* __restrict__ cpart,
                       float* __restrict__ G0, float* __restrict__ c0) {
    if (blockIdx.x < 64) {
        int e0 = (blockIdx.x * 256 + threadIdx.x) * 4;
        float4 s = make_float4(0.f, 0.f, 0.f, 0.f);
        for (int z = 0; z < NZ; ++z) {
            float4 v = *(const float4*)&Gp[(size_t)z * (FD * FD) + e0];
            s.x += v.x; s.y += v.y; s.z += v.z; s.w += v.w;
        }
        *(float4*)&G0[e0] = s;
    } else {
        float s = 0.f;
        for (int z = 0; z < NZ; ++z) s += cpart[z*FD + threadIdx.x];
        c0[threadIdx.x] = s;
    }
}

// emb'[j] = r_j + (r_j@G0 - (r_j.c0) r_j)/N , r_j = f0_j X_j.
// Emits nrm1[row] = ||emb'_row||^2 and fpart1[block].
__global__ void __launch_bounds__(256, 2)
k_apply(const float* __restrict__ X, const float* __restrict__ nrm0,
        const float* __restrict__ scal, const float* __restrict__ G0,
        const float* __restrict__ c0, float* __restrict__ emb,
        float* __restrict__ nrm1, float* __restrict__ fpart1) {
    __shared__ float rows[16][FD + 4];
    __shared__ float csh[FD];
    __shared__ float ff[16];
    __shared__ float u0[16];
    __shared__ float np[4][16];
    const int tid = threadIdx.x;
    const int r0 = blockIdx.x * 16;
    const float A = scal[4], B = scal[5], AB = scal[6];

    csh[tid] = c0[tid];
    if (tid < 16) ff[tid] = f_of(nrm0[r0 + tid], A, B, AB);
    __syncthreads();

    #pragma unroll
    for (int r = 0; r < 4; ++r) {
        int idx = tid + r * 256;
        int j = idx >> 6, c4 = (idx & 63) << 2;
        float4 v = *(const float4*)&X[(size_t)(r0 + j) * FD + c4];
        float f = ff[j];
        v.x *= f; v.y *= f; v.z *= f; v.w *= f;
        *(float4*)&rows[j][c4] = v;
    }
    __syncthreads();

    const int wave = tid >> 6, lane = tid & 63;
    #pragma unroll
    for (int jj = 0; jj < 4; ++jj) {
        int j = wave * 4 + jj;
        float4 rv = *(const float4*)&rows[j][lane*4];
        float4 cc = *(const float4*)&csh[lane*4];
        float s = rv.x*cc.x + rv.y*cc.y + rv.z*cc.z + rv.w*cc.w;
        #pragma unroll
        for (int off = 32; off; off >>= 1) s += __shfl_down(s, off);
        if (lane == 0) u0[j] = s;
    }
    __syncthreads();

    const int rq = lane >> 4, cx = lane & 15;
    const int c0w = wave * 64 + cx * 4;
    const int jb = rq * 4;
    float acc[4][4] = {};
    #pragma unroll 4
    for (int m = 0; m < FD; m += 4) {
        float4 g0 = *(const float4*)&G0[(m+0)*FD + c0w];
        float4 g1 = *(const float4*)&G0[(m+1)*FD + c0w];
        float4 g2 = *(const float4*)&G0[(m+2)*FD + c0w];
        float4 g3 = *(const float4*)&G0[(m+3)*FD + c0w];
        #pragma unroll
        for (int jj = 0; jj < 4; ++jj) {
            float4 rv = *(const float4*)&rows[jb + jj][m];
            acc[jj][0] += rv.x*g0.x + rv.y*g1.x + rv.z*g2.x + rv.w*g3.x;
            acc[jj][1] += rv.x*g0.y + rv.y*g1.y + rv.z*g2.y + rv.w*g3.y;
            acc[jj][2] += rv.x*g0.z + rv.y*g1.z + rv.z*g2.z + rv.w*g3.z;
            acc[jj][3] += rv.x*g0.w + rv.y*g1.w + rv.z*g2.w + rv.w*g3.w;
        }
    }

    const float invN = 1.0f / NROW;
    float ssl[4];
    #pragma unroll
    for (int jj = 0; jj < 4; ++jj) {
        int j = jb + jj;
        float4 v = *(const float4*)&rows[j][c0w];
        float uj = u0[j];
        float4 o;
        o.x = v.x + (acc[jj][0] - uj*v.x) * invN;
        o.y = v.y + (acc[jj][1] - uj*v.y) * invN;
        o.z = v.z + (acc[jj][2] - uj*v.z) * invN;
        o.w = v.w + (acc[jj][3] - uj*v.w) * invN;
        *(float4*)&emb[(size_t)(r0 + j) * FD + c0w] = o;
        ssl[jj] = o.x*o.x + o.y*o.y + o.z*o.z + o.w*o.w;
    }
    // reduce ss over cx (16-lane groups), then across waves via LDS
    #pragma unroll
    for (int jj = 0; jj < 4; ++jj) {
        float s = ssl[jj];
        #pragma unroll
        for (int off = 8; off; off >>= 1) s += __shfl_down(s, off);
        if (cx == 0) np[wave][jb + jj] = s;
    }
    __syncthreads();
    if (tid < 16) {
        float nn = np[0][tid] + np[1][tid] + np[2][tid] + np[3][tid];
        nrm1[r0 + tid] = nn;
        ff[tid] = nn;                       // reuse as scratch
    }
    __syncthreads();
    if (tid == 0) {
        float fp = 0.f;
        #pragma unroll
        for (int j = 0; j < 16; ++j) fp += ff[j];
        fpart1[blockIdx.x] = fp;
    }
}

// depth-1 scalars recomputed per block from fpart1 (cheap; saves a dispatch)
__device__ __forceinline__ void red1_scal(const float* fpart1, const float* scal,
                                          float* l, float& A, float& B, float& AB) {
    int tid = threadIdx.x;
    float s = 0.f;
    for (int j = tid; j < 512; j += 256) s += fpart1[j];
    l[tid] = s;
    __syncthreads();
    for (int off = 128; off; off >>= 1) {
        if (tid < off) l[tid] += l[tid + off];
        __syncthreads();
    }
    float F2 = l[0];
    float a = scal[1], b = scal[3];
    float sb = (b > 0.f) ? 1.f : ((b < 0.f) ? -1.f : 0.f);
    B = sb / sqrtf(F2);
    A = a; AB = a * B;
    __syncthreads();
}

// spart[bid][col] = sum_{j in 64 rows} f1_j emb'[j][col]
__global__ void k_colsum(const float* __restrict__ emb, const float* __restrict__ nrm1,
                         const float* __restrict__ scal, const float* __restrict__ fpart1,
                         float* __restrict__ spart) {
    __shared__ float l[256];
    float A, B, AB;
    red1_scal(fpart1, scal, l, A, B, AB);
    int tid = threadIdx.x;
    int r0 = blockIdx.x * 64;
    float s = 0.f;
    for (int j = 0; j < 64; ++j) {
        int row = r0 + j;
        float f = f_of(nrm1[row], A, B, AB);
        s += f * emb[(size_t)row * FD + tid];
    }
    spart[(size_t)blockIdx.x * FD + tid] = s;
}

// u[row] = f1 (emb'_row . s) ; vpart[bid][col] = sum_j (u_j f1_j) emb'[j][col]
__global__ void k_uv(const float* __restrict__ emb, const float* __restrict__ nrm1,
                     const float* __restrict__ scal, const float* __restrict__ fpart1,
                     const float* __restrict__ spart, float* __restrict__ u,
                     float* __restrict__ vpart) {
    __shared__ float l[256];
    __shared__ float ssh[FD];
    __shared__ float uf[64];
    float A, B, AB;
    red1_scal(fpart1, scal, l, A, B, AB);
    int tid = threadIdx.x;
    int r0 = blockIdx.x * 64;
    float sc = 0.f;
    for (int b = 0; b < 128; ++b) sc += spart[(size_t)b * FD + tid];
    ssh[tid] = sc;
    __syncthreads();
    const int wave = tid >> 6, lane = tid & 63;
    float4 sv = *(const float4*)&ssh[lane*4];
    #pragma unroll 4
    for (int jj = 0; jj < 16; ++jj) {
        int row = r0 + wave * 16 + jj;
        float4 ev = *(const float4*)&emb[(size_t)row * FD + lane*4];
        float s = ev.x*sv.x + ev.y*sv.y + ev.z*sv.z + ev.w*sv.w;
        #pragma unroll
        for (int off = 32; off; off >>= 1) s += __shfl_down(s, off);
        if (lane == 0) {
            float f = f_of(nrm1[row], A, B, AB);
            float uj = f * s;
            u[row] = uj;
            uf[wave*16 + jj] = uj * f;
        }
    }
    __syncthreads();
    float vp = 0.f;
    for (int j = 0; j < 64; ++j)
        vp += uf[j] * emb[(size_t)(r0 + j) * FD + tid];
    vpart[(size_t)blockIdx.x * FD + tid] = vp;
}

// out[row] = (u + (f1*(emb'_row . v) - u^2)/N)/N   for row < N-1
__global__ void k_out(const float* __restrict__ emb, const float* __restrict__ nrm1,
                      const float* __restrict__ scal, const float* __restrict__ fpart1,
                      const float* __restrict__ vpart, const float* __restrict__ u,
                      float* __restrict__ out) {
    __shared__ float l[256];
    __shared__ float vsh[FD];
    float A, B, AB;
    red1_scal(fpart1, scal, l, A, B, AB);
    int tid = threadIdx.x;
    int r0 = blockIdx.x * 64;
    float vc = 0.f;
    for (int b = 0; b < 128; ++b) vc += vpart[(size_t)b * FD + tid];
    vsh[tid] = vc;
    __syncthreads();
    const int wave = tid >> 6, lane = tid & 63;
    const float invN = 1.0f / NROW;
    float4 vv = *(const float4*)&vsh[lane*4];
    #pragma unroll 4
    for (int jj = 0; jj < 16; ++jj) {
        int row = r0 + wave * 16 + jj;
        float4 ev = *(const float4*)&emb[(size_t)row * FD + lane*4];
        float s = ev.x*vv.x + ev.y*vv.y + ev.z*vv.z + ev.w*vv.w;
        #pragma unroll
        for (int off = 32; off; off >>= 1) s += __shfl_down(s, off);
        if (lane == 0 && row < NROW - 1) {
            float f = f_of(nrm1[row], A, B, AB);
            float uj = u[row];
            out[row] = (uj + (f * s - uj * uj) * invN) * invN;
        }
    }
}

extern "C" void kernel_launch(void* const* d_in, const int* in_sizes, int n_in,
                              void* d_out, int out_size, void* d_ws, size_t ws_size,
                              hipStream_t stream) {
    const float* X      = (const float*)d_in[0];
    // d_in[1] = coefs (unused by the reference forward)
    const float* linear = (const float*)d_in[2];
    const float* dirv   = (const float*)d_in[3];
    const float* feat   = (const float*)d_in[4];
    float* out = (float*)d_out;

    char* ws = (char*)d_ws;
    float* scal   = (float*)(ws + 0);
    float* nrm0   = (float*)(ws + 4096);
    float* nrm1   = (float*)(ws + 36864);
    float* fpart  = (float*)(ws + 69632);   // also fpart1[512] after red0
    float* cpart  = (float*)(ws + 77824);
    float* c0     = (float*)(ws + 110592);
    float* G0     = (float*)(ws + 112640);
    float* spart  = (float*)(ws + 375808);
    float* u      = (float*)(ws + 506880);
    float* vpart  = (float*)(ws + 539648);
    float* emb    = (float*)(ws + 1048576);
    float* Gp     = emb;                    // Gp0 lives in emb region pre-apply

    k_norm<<<NROW/4, 256, 0, stream>>>(X, nrm0, fpart);
    k_red<<<1, 256, 0, stream>>>(fpart, 2048, scal, 0, linear, dirv, feat, 1);
    k_gram<<<dim3(4,4,NZ), 256, 0, stream>>>(X, nrm0, scal, Gp, cpart);
    k_gred<<<65, 256, 0, stream>>>(Gp, cpart, G0, c0);
    k_apply<<<NROW/16, 256, 0, stream>>>(X, nrm0, scal, G0, c0, emb, nrm1, fpart);
    k_colsum<<<128, 256, 0, stream>>>(emb, nrm1, scal, fpart, spart);
    k_uv<<<128, 256, 0, stream>>>(emb, nrm1, scal, fpart, spart, u, vpart);
    k_out<<<128, 256, 0, stream>>>(emb, nrm1, scal, fpart, vpart, u, out);
}

// Round 4
// 163.545 us; speedup vs baseline: 2.0217x; 1.0954x over previous
//
#include <hip/hip_runtime.h>
#include <math.h>

constexpr int NROW = 8192;
constexpr int FD   = 256;
constexpr int NZ   = 32;

// ws layout (bytes):
//   0       : float scal[8]  {a0,a1,b0,b1,A,B,AB,F2}
//   4096    : float nrm0[8192]    (32 KB)
//   36864   : float nrm1[8192]    (32 KB)
//   69632   : float fpart[2048]   (8 KB)
//   77824   : float fpart1[512]   (2 KB)
//   79872   : float cpart[32*256] (32 KB)
//   112640  : float c0[256]       (1 KB)
//   113664  : float svec[256]     (1 KB)
//   114688  : float vvec[256]     (1 KB)
//   115712  : float u[8192]       (32 KB)
//   148480  : float G0[65536]     (256 KB)  ends 410624
//   524288  : float spart[512*256] (512 KB; vpart aliases it)
//   1048576 : float emb[8192*256] (8 MB)  — Gp[32][65536] aliases it pre-apply

__device__ __forceinline__ float f_of(float nj, float A, float B, float AB) {
    float inner = AB * nj;
    return A - (inner <= 0.f ? inner : 0.f) * B;
}

// one wave per row: nrm0[j] = ||row||^2 ; block partial -> fpart
__global__ void k_norm(const float* __restrict__ in, float* __restrict__ nrm,
                       float* __restrict__ fpart) {
    __shared__ float bs[4];
    int wave = threadIdx.x >> 6, lane = threadIdx.x & 63;
    int row = blockIdx.x * 4 + wave;
    const float4 v = *(const float4*)&in[(size_t)row * FD + lane * 4];
    float s = v.x*v.x + v.y*v.y + v.z*v.z + v.w*v.w;
    #pragma unroll
    for (int off = 32; off; off >>= 1) s += __shfl_down(s, off);
    if (lane == 0) { nrm[row] = s; bs[wave] = s; }
    __syncthreads();
    if (threadIdx.x == 0) fpart[blockIdx.x] = bs[0] + bs[1] + bs[2] + bs[3];
}

// 1 block: a,b dots; F2 = sum(fpart); scalars A,B,AB for depth 0
__global__ void k_red(const float* __restrict__ fpart, int n, float* __restrict__ scal,
                      const float* __restrict__ linear, const float* __restrict__ dirv,
                      const float* __restrict__ feat) {
    __shared__ float l[256];
    int tid = threadIdx.x;
    if (tid < 64) {
        for (int i = 0; i < 2; ++i) {
            float pa = 0.f, pb = 0.f;
            for (int k = tid; k < FD; k += 64) {
                float ll = linear[i*FD + k];
                pa += feat[i*FD + k] * ll;
                pb += dirv[i*FD + k] * ll;
            }
            #pragma unroll
            for (int off = 32; off; off >>= 1) {
                pa += __shfl_down(pa, off);
                pb += __shfl_down(pb, off);
            }
            if (tid == 0) { scal[i] = pa; scal[2 + i] = pb; }
        }
    }
    float s = 0.f;
    for (int j = tid; j < n; j += 256) s += fpart[j];
    l[tid] = s;
    __syncthreads();
    for (int off = 128; off; off >>= 1) {
        if (tid < off) l[tid] += l[tid + off];
        __syncthreads();
    }
    if (tid == 0) {
        float F2 = l[0];
        float a = scal[0], b = scal[2];
        float sb = (b > 0.f) ? 1.f : ((b < 0.f) ? -1.f : 0.f);
        float B = sb / sqrtf(F2);
        scal[4] = a; scal[5] = B; scal[6] = a * B; scal[7] = F2;
    }
}

// Gram partials of r0 = f0*X: grid (8,4,32); 32x64 output tile, K=256 rows per z.
// tj==0 blocks emit cpart[z][ti*32..+32] = colsum of scaled rows in their K-range.
__global__ void __launch_bounds__(256, 4)
k_gram(const float* __restrict__ X, const float* __restrict__ nrm0,
       const float* __restrict__ scal, float* __restrict__ Gp,
       float* __restrict__ cpart) {
    __shared__ float As[32][36];   // padded: stride 36 kills b128 staging conflicts
    __shared__ float Bs[32][68];
    __shared__ float frow[32];
    __shared__ float csr[8][32];
    const int ti = blockIdx.x, tj = blockIdx.y, z = blockIdx.z;
    const int m0 = z * (NROW / NZ);            // 256 rows per z
    const int tid = threadIdx.x;
    const int tx = tid & 15, ty = tid >> 4;    // cols tx*4.., rows ty*2..
    const int p = tid & 31, q = tid >> 5;
    const float A = scal[4], B = scal[5], AB = scal[6];
    float acc[2][4] = {};
    float cs = 0.f;
    for (int mc = m0; mc < m0 + (NROW / NZ); mc += 32) {
        __syncthreads();
        if (tid < 32) frow[tid] = f_of(nrm0[mc + tid], A, B, AB);
        __syncthreads();
        {   // stage A: 32x32, one float4/thread
            int mm = tid >> 3, c4 = (tid & 7) << 2;
            float f = frow[mm];
            float4 a = *(const float4*)&X[(size_t)(mc + mm) * FD + ti*32 + c4];
            a.x *= f; a.y *= f; a.z *= f; a.w *= f;
            *(float4*)&As[mm][c4] = a;
        }
        #pragma unroll
        for (int r = 0; r < 2; ++r) {   // stage B: 32x64, two float4/thread
            int idx = tid + r * 256;
            int mm = idx >> 4, c4 = (idx & 15) << 2;
            float f = frow[mm];
            float4 b = *(const float4*)&X[(size_t)(mc + mm) * FD + tj*64 + c4];
            b.x *= f; b.y *= f; b.z *= f; b.w *= f;
            *(float4*)&Bs[mm][c4] = b;
        }
        __syncthreads();
        #pragma unroll 8
        for (int mm = 0; mm < 32; ++mm) {
            float2 a2 = *(const float2*)&As[mm][ty*2];
            float4 b4 = *(const float4*)&Bs[mm][tx*4];
            acc[0][0] += a2.x*b4.x; acc[0][1] += a2.x*b4.y;
            acc[0][2] += a2.x*b4.z; acc[0][3] += a2.x*b4.w;
            acc[1][0] += a2.y*b4.x; acc[1][1] += a2.y*b4.y;
            acc[1][2] += a2.y*b4.z; acc[1][3] += a2.y*b4.w;
        }
        if (tj == 0) {
            #pragma unroll
            for (int s = 0; s < 4; ++s) cs += As[q*4 + s][p];
        }
    }
    float* gp = Gp + (size_t)z * (FD * FD);
    #pragma unroll
    for (int r = 0; r < 2; ++r) {
        float4 o = make_float4(acc[r][0], acc[r][1], acc[r][2], acc[r][3]);
        *(float4*)&gp[(ti*32 + ty*2 + r)*FD + tj*64 + tx*4] = o;
    }
    if (tj == 0) {
        csr[q][p] = cs;
        __syncthreads();
        if (tid < 32) {
            float s = 0.f;
            #pragma unroll
            for (int qq = 0; qq < 8; ++qq) s += csr[qq][tid];
            cpart[z*FD + ti*32 + tid] = s;
        }
    }
}

// blocks 0..255: G0[bid*256+tid] = sum_z Gp ; block 256: c0 = sum_z cpart
__global__ void k_gred(const float* __restrict__ Gp, const float* __restrict__ cpart,
                       float* __restrict__ G0, float* __restrict__ c0) {
    int tid = threadIdx.x;
    if (blockIdx.x < 256) {
        int e0 = blockIdx.x * 256 + tid;
        float s = 0.f;
        #pragma unroll 8
        for (int z = 0; z < NZ; ++z) s += Gp[(size_t)z * (FD * FD) + e0];
        G0[e0] = s;
    } else {
        float s = 0.f;
        #pragma unroll 8
        for (int z = 0; z < NZ; ++z) s += cpart[z*FD + tid];
        c0[tid] = s;
    }
}

// emb'[j] = r_j + (r_j@G0 - (r_j.c0) r_j)/N , r_j = f0_j X_j. 512 thr, 16 rows/block.
// Emits nrm1[row], fpart1[bid].
__global__ void __launch_bounds__(512, 4)
k_apply(const float* __restrict__ X, const float* __restrict__ nrm0,
        const float* __restrict__ scal, const float* __restrict__ G0,
        const float* __restrict__ c0, float* __restrict__ emb,
        float* __restrict__ nrm1, float* __restrict__ fpart1) {
    __shared__ float rows[16][FD + 4];
    __shared__ float csh[FD];
    __shared__ float ff[16];
    __shared__ float u0[16];
    __shared__ float np[8][16];
    const int tid = threadIdx.x;
    const int r0 = blockIdx.x * 16;
    const float A = scal[4], B = scal[5], AB = scal[6];

    if (tid < FD) csh[tid] = c0[tid];
    if (tid < 16) ff[tid] = f_of(nrm0[r0 + tid], A, B, AB);
    __syncthreads();

    #pragma unroll
    for (int r = 0; r < 2; ++r) {
        int idx = tid + r * 512;
        int j = idx >> 6, c4 = (idx & 63) << 2;
        float4 v = *(const float4*)&X[(size_t)(r0 + j) * FD + c4];
        float f = ff[j];
        v.x *= f; v.y *= f; v.z *= f; v.w *= f;
        *(float4*)&rows[j][c4] = v;
    }
    __syncthreads();

    const int wave = tid >> 6, lane = tid & 63;
    #pragma unroll
    for (int jj = 0; jj < 2; ++jj) {
        int j = wave * 2 + jj;
        float4 rv = *(const float4*)&rows[j][lane*4];
        float4 cc = *(const float4*)&csh[lane*4];
        float s = rv.x*cc.x + rv.y*cc.y + rv.z*cc.z + rv.w*cc.w;
        #pragma unroll
        for (int off = 32; off; off >>= 1) s += __shfl_down(s, off);
        if (lane == 0) u0[j] = s;
    }
    __syncthreads();

    const int rq = lane >> 4, cx = lane & 15;
    const int half = wave >> 2;                // row half (0: rows 0-7, 1: 8-15)
    const int c0w = (wave & 3) * 64 + cx * 4;  // 4 output cols
    const int jb = half * 8 + rq * 2;          // 2 rows
    float acc[2][4] = {};
    #pragma unroll 4
    for (int m = 0; m < FD; m += 4) {
        float4 g0 = *(const float4*)&G0[(m+0)*FD + c0w];
        float4 g1 = *(const float4*)&G0[(m+1)*FD + c0w];
        float4 g2 = *(const float4*)&G0[(m+2)*FD + c0w];
        float4 g3 = *(const float4*)&G0[(m+3)*FD + c0w];
        #pragma unroll
        for (int jj = 0; jj < 2; ++jj) {
            float4 rv = *(const float4*)&rows[jb + jj][m];
            acc[jj][0] += rv.x*g0.x + rv.y*g1.x + rv.z*g2.x + rv.w*g3.x;
            acc[jj][1] += rv.x*g0.y + rv.y*g1.y + rv.z*g2.y + rv.w*g3.y;
            acc[jj][2] += rv.x*g0.z + rv.y*g1.z + rv.z*g2.z + rv.w*g3.z;
            acc[jj][3] += rv.x*g0.w + rv.y*g1.w + rv.z*g2.w + rv.w*g3.w;
        }
    }

    const float invN = 1.0f / NROW;
    float ssl[2];
    #pragma unroll
    for (int jj = 0; jj < 2; ++jj) {
        int j = jb + jj;
        float4 v = *(const float4*)&rows[j][c0w];
        float uj = u0[j];
        float4 o;
        o.x = v.x + (acc[jj][0] - uj*v.x) * invN;
        o.y = v.y + (acc[jj][1] - uj*v.y) * invN;
        o.z = v.z + (acc[jj][2] - uj*v.z) * invN;
        o.w = v.w + (acc[jj][3] - uj*v.w) * invN;
        *(float4*)&emb[(size_t)(r0 + j) * FD + c0w] = o;
        ssl[jj] = o.x*o.x + o.y*o.y + o.z*o.z + o.w*o.w;
    }
    #pragma unroll
    for (int jj = 0; jj < 2; ++jj) {
        float s = ssl[jj];
        #pragma unroll
        for (int off = 8; off; off >>= 1) s += __shfl_down(s, off);
        if (cx == 0) np[wave][jb + jj] = s;
    }
    __syncthreads();
    if (tid < 16) {
        int h = tid >> 3;
        float nn = np[h*4+0][tid] + np[h*4+1][tid] + np[h*4+2][tid] + np[h*4+3][tid];
        nrm1[r0 + tid] = nn;
        ff[tid] = nn;
    }
    __syncthreads();
    if (tid == 0) {
        float fp = 0.f;
        #pragma unroll
        for (int j = 0; j < 16; ++j) fp += ff[j];
        fpart1[blockIdx.x] = fp;
    }
}

// depth-1 scalars recomputed per block from fpart1[512]
__device__ __forceinline__ void red1_scal(const float* fpart1, const float* scal,
                                          float* l, float& A, float& B, float& AB) {
    int tid = threadIdx.x;
    float s = fpart1[tid] + fpart1[tid + 256];
    l[tid] = s;
    __syncthreads();
    for (int off = 128; off; off >>= 1) {
        if (tid < off) l[tid] += l[tid + off];
        __syncthreads();
    }
    float F2 = l[0];
    float a = scal[1], b = scal[3];
    float sb = (b > 0.f) ? 1.f : ((b < 0.f) ? -1.f : 0.f);
    B = sb / sqrtf(F2);
    A = a; AB = a * B;
    __syncthreads();
}

// spart[bid][col] = sum_{16 rows} f1_j emb'[j][col]
__global__ void k_colsum(const float* __restrict__ emb, const float* __restrict__ nrm1,
                         const float* __restrict__ scal, const float* __restrict__ fpart1,
                         float* __restrict__ spart) {
    __shared__ float l[256];
    __shared__ float ffs[16];
    float A, B, AB;
    red1_scal(fpart1, scal, l, A, B, AB);
    int tid = threadIdx.x;
    int r0 = blockIdx.x * 16;
    if (tid < 16) ffs[tid] = f_of(nrm1[r0 + tid], A, B, AB);
    __syncthreads();
    float s = 0.f;
    #pragma unroll
    for (int j = 0; j < 16; ++j)
        s += ffs[j] * emb[(size_t)(r0 + j) * FD + tid];
    spart[(size_t)blockIdx.x * FD + tid] = s;
}

// reduce part[512][256] -> vec[256]; grid 64 x 256 thr (4 cols/block)
__global__ void k_sred(const float* __restrict__ part, float* __restrict__ vec) {
    int tid = threadIdx.x;
    int col = blockIdx.x * 4 + (tid >> 6);
    int lane = tid & 63;
    float s = 0.f;
    #pragma unroll
    for (int b = 0; b < 8; ++b) s += part[(size_t)(b * 64 + lane) * FD + col];
    #pragma unroll
    for (int off = 32; off; off >>= 1) s += __shfl_down(s, off);
    if (lane == 0) vec[col] = s;
}

// u[row] = f1 (emb'_row . s) ; vpart[bid][col] = sum_j (u_j f1_j) emb'[j][col]
__global__ void k_uv(const float* __restrict__ emb, const float* __restrict__ nrm1,
                     const float* __restrict__ scal, const float* __restrict__ fpart1,
                     const float* __restrict__ svec, float* __restrict__ u,
                     float* __restrict__ vpart) {
    __shared__ float l[256];
    __shared__ float ssh[FD];
    __shared__ float uf[16];
    float A, B, AB;
    red1_scal(fpart1, scal, l, A, B, AB);
    int tid = threadIdx.x;
    int r0 = blockIdx.x * 16;
    ssh[tid] = svec[tid];
    __syncthreads();
    const int wave = tid >> 6, lane = tid & 63;
    float4 sv = *(const float4*)&ssh[lane*4];
    #pragma unroll
    for (int jj = 0; jj < 4; ++jj) {
        int row = r0 + wave * 4 + jj;
        float4 ev = *(const float4*)&emb[(size_t)row * FD + lane*4];
        float s = ev.x*sv.x + ev.y*sv.y + ev.z*sv.z + ev.w*sv.w;
        #pragma unroll
        for (int off = 32; off; off >>= 1) s += __shfl_down(s, off);
        if (lane == 0) {
            float f = f_of(nrm1[row], A, B, AB);
            float uj = f * s;
            u[row] = uj;
            uf[wave*4 + jj] = uj * f;
        }
    }
    __syncthreads();
    float vp = 0.f;
    #pragma unroll
    for (int j = 0; j < 16; ++j)
        vp += uf[j] * emb[(size_t)(r0 + j) * FD + tid];
    vpart[(size_t)blockIdx.x * FD + tid] = vp;
}

// out[row] = (u + (f1*(emb'_row . v) - u^2)/N)/N
__global__ void k_out(const float* __restrict__ emb, const float* __restrict__ nrm1,
                      const float* __restrict__ scal, const float* __restrict__ fpart1,
                      const float* __restrict__ vvec, const float* __restrict__ u,
                      float* __restrict__ out) {
    __shared__ float l[256];
    __shared__ float vsh[FD];
    float A, B, AB;
    red1_scal(fpart1, scal, l, A, B, AB);
    int tid = threadIdx.x;
    int r0 = blockIdx.x * 16;
    vsh[tid] = vvec[tid];
    __syncthreads();
    const int wave = tid >> 6, lane = tid & 63;
    const float invN = 1.0f / NROW;
    float4 vv = *(const float4*)&vsh[lane*4];
    #pragma unroll
    for (int jj = 0; jj < 4; ++jj) {
        int row = r0 + wave * 4 + jj;
        float4 ev = *(const float4*)&emb[(size_t)row * FD + lane*4];
        float s = ev.x*vv.x + ev.y*vv.y + ev.z*vv.z + ev.w*vv.w;
        #pragma unroll
        for (int off = 32; off; off >>= 1) s += __shfl_down(s, off);
        if (lane == 0 && row < NROW - 1) {
            float f = f_of(nrm1[row], A, B, AB);
            float uj = u[row];
            out[row] = (uj + (f * s - uj * uj) * invN) * invN;
        }
    }
}

extern "C" void kernel_launch(void* const* d_in, const int* in_sizes, int n_in,
                              void* d_out, int out_size, void* d_ws, size_t ws_size,
                              hipStream_t stream) {
    const float* X      = (const float*)d_in[0];
    // d_in[1] = coefs (unused by the reference forward)
    const float* linear = (const float*)d_in[2];
    const float* dirv   = (const float*)d_in[3];
    const float* feat   = (const float*)d_in[4];
    float* out = (float*)d_out;

    char* ws = (char*)d_ws;
    float* scal   = (float*)(ws + 0);
    float* nrm0   = (float*)(ws + 4096);
    float* nrm1   = (float*)(ws + 36864);
    float* fpart  = (float*)(ws + 69632);
    float* fpart1 = (float*)(ws + 77824);
    float* cpart  = (float*)(ws + 79872);
    float* c0     = (float*)(ws + 112640);
    float* svec   = (float*)(ws + 113664);
    float* vvec   = (float*)(ws + 114688);
    float* u      = (float*)(ws + 115712);
    float* G0     = (float*)(ws + 148480);
    float* spart  = (float*)(ws + 524288);   // vpart aliases spart
    float* emb    = (float*)(ws + 1048576);
    float* Gp     = emb;                     // Gp lives in emb region pre-apply

    k_norm<<<NROW/4, 256, 0, stream>>>(X, nrm0, fpart);
    k_red<<<1, 256, 0, stream>>>(fpart, 2048, scal, linear, dirv, feat);
    k_gram<<<dim3(8,4,NZ), 256, 0, stream>>>(X, nrm0, scal, Gp, cpart);
    k_gred<<<257, 256, 0, stream>>>(Gp, cpart, G0, c0);
    k_apply<<<NROW/16, 512, 0, stream>>>(X, nrm0, scal, G0, c0, emb, nrm1, fpart1);
    k_colsum<<<NROW/16, 256, 0, stream>>>(emb, nrm1, scal, fpart1, spart);
    k_sred<<<64, 256, 0, stream>>>(spart, svec);
    k_uv<<<NROW/16, 256, 0, stream>>>(emb, nrm1, scal, fpart1, svec, u, spart);
    k_sred<<<64, 256, 0, stream>>>(spart, vvec);
    k_out<<<NROW/16, 256, 0, stream>>>(emb, nrm1, scal, fpart1, vvec, u, out);
}